// Round 2
// baseline (495.885 us; speedup 1.0000x reference)
//
#include <hip/hip_runtime.h>
#include <stdint.h>

typedef short bf16x8 __attribute__((ext_vector_type(8)));
typedef float f32x4 __attribute__((ext_vector_type(4)));

#define ASYNC16(g, l) __builtin_amdgcn_global_load_lds( \
    (const __attribute__((address_space(1))) unsigned int*)(g), \
    (__attribute__((address_space(3))) unsigned int*)(l), 16, 0, 0)

__device__ __forceinline__ float bf2f(short u) {
  union { unsigned int i; float f; } v;
  v.i = ((unsigned int)(unsigned short)u) << 16;
  return v.f;
}
__device__ __forceinline__ short f2bf(float f) {
  union { float f; unsigned int i; } v;
  v.f = f;
  return (short)(unsigned short)((v.i + 0x8000u) >> 16);
}
__device__ __forceinline__ float ldf(const void* p, long i, int isbf) {
  return isbf ? bf2f(((const short*)p)[i]) : ((const float*)p)[i];
}

// ---------------------------------------------------------------------------
__global__ void detect_dtype(const short* __restrict__ x, int* __restrict__ flag) {
  if (threadIdx.x == 0 && blockIdx.x == 0) {
    int cnt = 0;
    for (int i = 0; i < 128; ++i) {
      int e = (((unsigned short)x[i]) >> 7) & 0xFF;
      if (e >= 110 && e <= 136) ++cnt;
    }
    *flag = (cnt >= 120) ? 1 : 0;
  }
}

__global__ __launch_bounds__(256) void convert_x(
    const void* __restrict__ xin, short* __restrict__ xb, const int* __restrict__ flag) {
  long i = (long)blockIdx.x * 2048 + (long)threadIdx.x * 8;
  if (*flag) {
    *(bf16x8*)(xb + i) = *(const bf16x8*)((const short*)xin + i);
  } else {
    const float* xf = (const float*)xin;
    short tmp[8];
    #pragma unroll
    for (int j = 0; j < 8; ++j) tmp[j] = f2bf(xf[i + j]);
    *(bf16x8*)(xb + i) = *(bf16x8*)tmp;
  }
}

// ---------------------------------------------------------------------------
__global__ __launch_bounds__(256) void transpose_w(
    const void* __restrict__ S0, short* __restrict__ D0,
    const void* __restrict__ S1, short* __restrict__ D1,
    const void* __restrict__ S2, short* __restrict__ D2,
    const int* __restrict__ flag)
{
  int z = blockIdx.z;
  const void* S = (z == 0) ? S0 : (z == 1) ? S1 : S2;
  short* D = (z == 0) ? D0 : (z == 1) ? D1 : D2;
  int isbf = *flag;
  __shared__ short tile[32][33];
  int c0 = blockIdx.x * 32, r0 = blockIdx.y * 32;
  int tx = threadIdx.x, ty = threadIdx.y;
  #pragma unroll
  for (int i = 0; i < 4; ++i)
    tile[ty + 8*i][tx] = f2bf(ldf(S, (long)(r0 + ty + 8*i) * 2048 + c0 + tx, isbf));
  __syncthreads();
  #pragma unroll
  for (int i = 0; i < 4; ++i)
    D[(long)(c0 + ty + 8*i) * 2048 + r0 + tx] = tile[tx][ty + 8*i];
}

__global__ __launch_bounds__(256) void transpose_v(
    const short* __restrict__ Vr, short* __restrict__ Vt)
{
  __shared__ short tile[32][33];
  int bh = blockIdx.z;
  int b = bh >> 4, h = bh & 15;
  int t0 = blockIdx.x * 32, d0 = blockIdx.y * 32;
  int tx = threadIdx.x, ty = threadIdx.y;
  #pragma unroll
  for (int i = 0; i < 4; ++i)
    tile[ty + 8*i][tx] = Vr[(long)(b*2048 + t0 + ty + 8*i) * 2048 + h*128 + d0 + tx];
  __syncthreads();
  #pragma unroll
  for (int i = 0; i < 4; ++i)
    Vt[((long)bh * 128 + d0 + ty + 8*i) * 2048 + t0 + tx] = tile[tx][ty + 8*i];
}

// ---------------------------------------------------------------------------
// GEMM: m201-faithful 256x256 tile, BK=64, 8 waves (2M x 4N), wave tile
// 128x64 (M_rep=8, N_rep=4).  LDS 128 KB = 2 dbuf x (A 256x64 + B 256x64).
// 4 fine phases per K-tile: {ds_read subtile, stage ONE half-tile (2 x
// global_load_lds), s_barrier, setprio(1), 16 MFMA, setprio(0), s_barrier}.
// Tile t+1's 4 half-tiles staged one-per-phase during tile t (its dbuf holds
// t-1's dead data -> race-free); single vmcnt(0) drain per K-tile at the
// last barrier (stages have ~3 phases of in-flight slack across barriers).
// XOR-octet swizzle folded into the global source (linear gload_lds dest):
// logical octet l of row r lives at phys octet l^(r&7); reads use
// po = ((kt*4+quad)^(l16&7))*8.  Measured 0 bank conflicts.
// ---------------------------------------------------------------------------
template<typename OutT>
__global__ __launch_bounds__(512, 2) void gemm_bt(
    const short* __restrict__ A,
    const short* __restrict__ B0, const short* __restrict__ B1, const short* __restrict__ B2,
    OutT* __restrict__ C0, OutT* __restrict__ C1, OutT* __restrict__ C2,
    int M, int N, int K)
{
  int z = blockIdx.z;
  const short* Bt = (z == 0) ? B0 : (z == 1) ? B1 : B2;
  OutT* C = (z == 0) ? C0 : (z == 1) ? C1 : C2;

  int m0 = blockIdx.y * 256, n0 = blockIdx.x * 256;
  int tid = threadIdx.x;
  int lane = tid & 63, w = tid >> 6;
  int quad = lane >> 4, l16 = lane & 15;
  int wm = w >> 2, wn = w & 3;            // wave tile: rows wm*128, cols wn*64

  __shared__ short As[2][256*64];         // 64 KB
  __shared__ short Bs[2][256*64];         // 64 KB

  f32x4 zero4 = {0.f, 0.f, 0.f, 0.f};
  f32x4 acc[8][4];
  #pragma unroll
  for (int i = 0; i < 8; ++i)
    #pragma unroll
    for (int j = 0; j < 4; ++j) acc[i][j] = zero4;

  // staging lane constants (swizzle on the global side; dest rows are
  // h*128 + w*16 + i*8 + (lane>>3), so row&7 == lane>>3)
  int r8 = lane >> 3;
  int oct = (lane & 7) ^ r8;
  const short* Ab = A  + (long)(m0 + w*16 + r8) * K + oct*8;
  const short* Bb = Bt + (long)(n0 + w*16 + r8) * K + oct*8;

  int NT = K >> 6;
  int po0 = ((0*4 + quad) ^ (l16 & 7)) * 8;
  int po1 = ((1*4 + quad) ^ (l16 & 7)) * 8;

  auto stA = [&](int sb, int h, long kn) {
    #pragma unroll
    for (int i = 0; i < 2; ++i)
      ASYNC16(Ab + (long)(h*128 + i*8) * K + kn, &As[sb][(h*128 + w*16 + i*8)*64]);
  };
  auto stB = [&](int sb, int h, long kn) {
    #pragma unroll
    for (int i = 0; i < 2; ++i)
      ASYNC16(Bb + (long)(h*128 + i*8) * K + kn, &Bs[sb][(h*128 + w*16 + i*8)*64]);
  };

  // prologue: stage K-tile 0 into dbuf 0
  stA(0, 0, 0); stA(0, 1, 0); stB(0, 0, 0); stB(0, 1, 0);
  asm volatile("s_waitcnt vmcnt(0)" ::: "memory");
  __builtin_amdgcn_s_barrier();

  bf16x8 am[8], bn0, bn1;

  for (int t = 0; t < NT; ++t) {
    int b = t & 1, sb = b ^ 1;
    long kn = (long)(t + 1) * 64;
    bool st = (t + 1 < NT);
    const short* Asb = &As[b][0];
    const short* Bsb = &Bs[b][0];

    // ---- phase 0: read A(kt0) x8 + B(kt0) nf0-1; stage A-half0 of t+1
    #pragma unroll
    for (int mf = 0; mf < 8; ++mf)
      am[mf] = *(const bf16x8*)&Asb[(wm*128 + mf*16 + l16)*64 + po0];
    bn0 = *(const bf16x8*)&Bsb[(wn*64 +  0 + l16)*64 + po0];
    bn1 = *(const bf16x8*)&Bsb[(wn*64 + 16 + l16)*64 + po0];
    if (st) stA(sb, 0, kn);
    __builtin_amdgcn_s_barrier();
    __builtin_amdgcn_s_setprio(1);
    #pragma unroll
    for (int mf = 0; mf < 8; ++mf)
      acc[mf][0] = __builtin_amdgcn_mfma_f32_16x16x32_bf16(am[mf], bn0, acc[mf][0], 0, 0, 0);
    #pragma unroll
    for (int mf = 0; mf < 8; ++mf)
      acc[mf][1] = __builtin_amdgcn_mfma_f32_16x16x32_bf16(am[mf], bn1, acc[mf][1], 0, 0, 0);
    __builtin_amdgcn_s_setprio(0);
    __builtin_amdgcn_s_barrier();

    // ---- phase 1: read B(kt0) nf2-3; stage A-half1
    bn0 = *(const bf16x8*)&Bsb[(wn*64 + 32 + l16)*64 + po0];
    bn1 = *(const bf16x8*)&Bsb[(wn*64 + 48 + l16)*64 + po0];
    if (st) stA(sb, 1, kn);
    __builtin_amdgcn_s_barrier();
    __builtin_amdgcn_s_setprio(1);
    #pragma unroll
    for (int mf = 0; mf < 8; ++mf)
      acc[mf][2] = __builtin_amdgcn_mfma_f32_16x16x32_bf16(am[mf], bn0, acc[mf][2], 0, 0, 0);
    #pragma unroll
    for (int mf = 0; mf < 8; ++mf)
      acc[mf][3] = __builtin_amdgcn_mfma_f32_16x16x32_bf16(am[mf], bn1, acc[mf][3], 0, 0, 0);
    __builtin_amdgcn_s_setprio(0);
    __builtin_amdgcn_s_barrier();

    // ---- phase 2: read A(kt1) x8 + B(kt1) nf0-1; stage B-half0
    #pragma unroll
    for (int mf = 0; mf < 8; ++mf)
      am[mf] = *(const bf16x8*)&Asb[(wm*128 + mf*16 + l16)*64 + po1];
    bn0 = *(const bf16x8*)&Bsb[(wn*64 +  0 + l16)*64 + po1];
    bn1 = *(const bf16x8*)&Bsb[(wn*64 + 16 + l16)*64 + po1];
    if (st) stB(sb, 0, kn);
    __builtin_amdgcn_s_barrier();
    __builtin_amdgcn_s_setprio(1);
    #pragma unroll
    for (int mf = 0; mf < 8; ++mf)
      acc[mf][0] = __builtin_amdgcn_mfma_f32_16x16x32_bf16(am[mf], bn0, acc[mf][0], 0, 0, 0);
    #pragma unroll
    for (int mf = 0; mf < 8; ++mf)
      acc[mf][1] = __builtin_amdgcn_mfma_f32_16x16x32_bf16(am[mf], bn1, acc[mf][1], 0, 0, 0);
    __builtin_amdgcn_s_setprio(0);
    __builtin_amdgcn_s_barrier();

    // ---- phase 3: read B(kt1) nf2-3; stage B-half1; tile-boundary drain
    bn0 = *(const bf16x8*)&Bsb[(wn*64 + 32 + l16)*64 + po1];
    bn1 = *(const bf16x8*)&Bsb[(wn*64 + 48 + l16)*64 + po1];
    if (st) stB(sb, 1, kn);
    __builtin_amdgcn_s_barrier();
    __builtin_amdgcn_s_setprio(1);
    #pragma unroll
    for (int mf = 0; mf < 8; ++mf)
      acc[mf][2] = __builtin_amdgcn_mfma_f32_16x16x32_bf16(am[mf], bn0, acc[mf][2], 0, 0, 0);
    #pragma unroll
    for (int mf = 0; mf < 8; ++mf)
      acc[mf][3] = __builtin_amdgcn_mfma_f32_16x16x32_bf16(am[mf], bn1, acc[mf][3], 0, 0, 0);
    __builtin_amdgcn_s_setprio(0);
    if (st) {
      asm volatile("s_waitcnt vmcnt(0)" ::: "memory");
      __builtin_amdgcn_s_barrier();
    }
  }

  #pragma unroll
  for (int mf = 0; mf < 8; ++mf)
    #pragma unroll
    for (int nf = 0; nf < 4; ++nf) {
      int row = m0 + wm*128 + mf*16 + quad*4;
      int col = n0 + wn*64 + nf*16 + l16;
      #pragma unroll
      for (int r = 0; r < 4; ++r) {
        float v = acc[mf][nf][r];
        if constexpr (sizeof(OutT) == 4)
          C[(long)(row + r) * N + col] = v;
        else
          C[(long)(row + r) * N + col] = (OutT)f2bf(v);
      }
    }
}

// ---------------------------------------------------------------------------
__global__ __launch_bounds__(256) void pointwise(
    const short* __restrict__ xb, const void* __restrict__ ve,
    const void* __restrict__ cosb, const void* __restrict__ sinb,
    const void* __restrict__ Wg, const int* __restrict__ flag,
    short* __restrict__ Qr, short* __restrict__ Kr, short* __restrict__ Vr)
{
  int row = blockIdx.x;
  int tid = threadIdx.x;
  int isbf = *flag;
  __shared__ float xg[32];
  __shared__ float gates[16];
  if (tid < 32) xg[tid] = bf2f(xb[(long)row * 2048 + tid]);
  __syncthreads();
  if (tid < 16) {
    float g = 0.f;
    #pragma unroll
    for (int i = 0; i < 32; ++i) g += xg[i] * ldf(Wg, i*16 + tid, isbf);
    gates[tid] = 2.0f / (1.0f + __expf(-g));
  }
  __syncthreads();
  #pragma unroll
  for (int it = 0; it < 8; ++it) {
    int idx = it * 256 + tid;
    int h = idx >> 7;
    long p = (long)row * 2048 + idx;
    Vr[p] = f2bf(bf2f(Vr[p]) + gates[h] * ldf(ve, p, isbf));
  }
  int lane = tid & 63, w = tid >> 6;
  int t = row & 2047;
  #pragma unroll
  for (int it = 0; it < 8; ++it) {
    int unit = it * 4 + w;
    short* P = (unit < 16) ? Qr : Kr;
    int h = unit & 15;
    long base = (long)row * 2048 + h * 128;
    float x1 = bf2f(P[base + lane]);
    float x2 = bf2f(P[base + lane + 64]);
    float c = ldf(cosb, t*64 + lane, isbf);
    float s = ldf(sinb, t*64 + lane, isbf);
    float r1 = x1 * c + x2 * s;
    float r2 = -x1 * s + x2 * c;
    float ss = r1*r1 + r2*r2;
    #pragma unroll
    for (int off = 32; off; off >>= 1) ss += __shfl_xor(ss, off);
    float rn = rsqrtf(ss * (1.0f/128.0f) + 1e-6f);
    P[base + lane]      = f2bf(r1 * rn);
    P[base + lane + 64] = f2bf(r2 * rn);
  }
}

// ---------------------------------------------------------------------------
// Flash v3 (+ T5 setprio around MFMA clusters)
// ---------------------------------------------------------------------------
#define FL_C1 0.12751741f
#define FL_C2 16.321698f

__global__ __launch_bounds__(256) void flash(
    const short* __restrict__ Q, const short* __restrict__ K,
    const short* __restrict__ Vt, short* __restrict__ Y)
{
  int bx = blockIdx.x;
  int bh = blockIdx.y;
  int b = bh >> 4, h = bh & 15;
  int tid = threadIdx.x;
  int lane = tid & 63, w = tid >> 6;
  int quad = lane >> 4, l16 = lane & 15;

  __shared__ short Ks[2][64*128];
  __shared__ short Vts[2][128*64];
  __shared__ short Ps[4][16*72];

  int qtA = bx, qtB = 31 - bx;
  int nA = qtA + 1, nB = qtB + 1;
  int total = nA + nB;

  int kkey = tid >> 4;
  int klo  = (tid & 15) ^ (kkey & 7);
  int vd   = tid >> 3;
  int vlo  = (tid & 7) ^ (vd & 7);
  const short* Kbase = K + (long)(b*2048 + kkey) * 2048 + h*128 + klo*8;
  const short* Vbase = Vt + ((long)bh*128 + vd) * 2048 + vlo*8;

  f32x4 zero4 = {0.f, 0.f, 0.f, 0.f};
  f32x4 o[8];
  float l_i[4];
  bf16x8 qf[4];
  bf16x8 ones;
  #pragma unroll
  for (int j = 0; j < 8; ++j) ones[j] = (short)0x3F80;

  auto stage = [&](int tt, int bufp) {
    int tl = (tt < nA) ? tt : tt - nA;
    long ko = (long)tl * 64 * 2048;
    int  vo = tl * 64;
    #pragma unroll
    for (int i = 0; i < 4; ++i)
      ASYNC16(Kbase + ko + (long)i*16*2048, &Ks[bufp][(i*16 + w*4)*128]);
    #pragma unroll
    for (int i = 0; i < 4; ++i)
      ASYNC16(Vbase + vo + (long)i*32*2048, &Vts[bufp][(i*32 + w*8)*64]);
  };
  auto loadQ = [&](int qt) {
    const short* Qb = Q + (long)(b*2048 + qt*64 + w*16 + l16) * 2048 + h*128;
    #pragma unroll
    for (int kt = 0; kt < 4; ++kt)
      qf[kt] = *(const bf16x8*)(Qb + kt*32 + quad*8);
  };
  auto flushO = [&](int qt) {
    #pragma unroll
    for (int r = 0; r < 4; ++r) {
      float inv = 1.0f / fmaxf(l_i[r], 1e-30f);
      short* yp = Y + (long)(b*2048 + qt*64 + w*16 + quad*4 + r) * 2048 + h*128;
      #pragma unroll
      for (int c8 = 0; c8 < 8; ++c8)
        yp[c8*16 + l16] = f2bf(o[c8][r] * inv);
    }
  };

  #pragma unroll
  for (int c = 0; c < 8; ++c) o[c] = zero4;
  #pragma unroll
  for (int r = 0; r < 4; ++r) l_i[r] = 0.f;
  loadQ(qtA);
  stage(0, 0);

  int qt = qtA, n_seg = nA, segbase = 0;
  for (int tt = 0; tt < total; ++tt) {
    int buf = tt & 1;
    asm volatile("s_waitcnt vmcnt(0)" ::: "memory");
    __builtin_amdgcn_s_barrier();
    if (tt + 1 < total) stage(tt + 1, buf ^ 1);
    if (tt == nA) {
      flushO(qtA);
      loadQ(qtB);
      #pragma unroll
      for (int c = 0; c < 8; ++c) o[c] = zero4;
      #pragma unroll
      for (int r = 0; r < 4; ++r) l_i[r] = 0.f;
      qt = qtB; n_seg = nB; segbase = nA;
    }
    int tloc = tt - segbase;
    int kv0 = tloc * 64;

    // S = Q K^T
    f32x4 s[4];
    __builtin_amdgcn_s_setprio(1);
    #pragma unroll
    for (int c = 0; c < 4; ++c) {
      f32x4 acc = zero4;
      #pragma unroll
      for (int kt = 0; kt < 4; ++kt) {
        int po = ((kt*4 + quad) ^ (l16 & 7)) * 8;
        bf16x8 kf = *(const bf16x8*)&Ks[buf][(c*16 + l16)*128 + po];
        acc = __builtin_amdgcn_mfma_f32_16x16x32_bf16(qf[kt], kf, acc, 0, 0, 0);
      }
      s[c] = acc;
    }
    __builtin_amdgcn_s_setprio(0);

    bool domask = (tloc == n_seg - 1);
    int qgb = qt*64 + w*16 + quad*4;
    #pragma unroll
    for (int c = 0; c < 4; ++c) {
      int kg = kv0 + c*16 + l16;
      #pragma unroll
      for (int r = 0; r < 4; ++r) {
        float t = s[c][r] * FL_C1 - FL_C2;
        if (domask && kg > qgb + r) t = -1000.0f;
        float pv = exp2f(t);
        Ps[w][(quad*4 + r)*72 + c*16 + l16] = f2bf(pv);
      }
    }
    asm volatile("s_waitcnt lgkmcnt(0)" ::: "memory");
    bf16x8 pa0 = *(const bf16x8*)&Ps[w][l16*72 + quad*8];
    bf16x8 pa1 = *(const bf16x8*)&Ps[w][l16*72 + 32 + quad*8];

    __builtin_amdgcn_s_setprio(1);
    f32x4 racc = __builtin_amdgcn_mfma_f32_16x16x32_bf16(pa0, ones, zero4, 0, 0, 0);
    racc = __builtin_amdgcn_mfma_f32_16x16x32_bf16(pa1, ones, racc, 0, 0, 0);
    #pragma unroll
    for (int r = 0; r < 4; ++r) l_i[r] += racc[r];

    #pragma unroll
    for (int c8 = 0; c8 < 8; ++c8) {
      int po0 = ((0*4 + quad) ^ (l16 & 7)) * 8;
      int po1 = ((1*4 + quad) ^ (l16 & 7)) * 8;
      bf16x8 v0 = *(const bf16x8*)&Vts[buf][(c8*16 + l16)*64 + po0];
      bf16x8 v1 = *(const bf16x8*)&Vts[buf][(c8*16 + l16)*64 + po1];
      o[c8] = __builtin_amdgcn_mfma_f32_16x16x32_bf16(pa0, v0, o[c8], 0, 0, 0);
      o[c8] = __builtin_amdgcn_mfma_f32_16x16x32_bf16(pa1, v1, o[c8], 0, 0, 0);
    }
    __builtin_amdgcn_s_setprio(0);
  }
  flushO(qtB);
}

// ---------------------------------------------------------------------------
extern "C" void kernel_launch(void* const* d_in, const int* in_sizes, int n_in,
                              void* d_out, int out_size, void* d_ws, size_t ws_size,
                              hipStream_t stream) {
  const void* x    = d_in[0];
  const void* ve   = d_in[1];
  const void* cosb = d_in[2];
  const void* sinb = d_in[3];
  const void* Wq   = d_in[4];
  const void* Wk   = d_in[5];
  const void* Wv   = d_in[6];
  const void* Wg   = d_in[7];
  const void* Wp   = d_in[8];
  float* out = (float*)d_out;

  int*   flag = (int*)d_ws;
  short* base = (short*)d_ws + 256;
  short* wt0 = base;                       // 4M: Wq^T, then Wp^T
  short* wtk = base + 4194304L;            // 4M: Wk^T (dead after QKV gemm)
  short* wtv = base + 8388608L;            // 4M: Wv^T (dead after QKV gemm)
  short* Vt  = base + 4194304L;            // 8M: aliases wtk+wtv
  short* xb  = base + 12582912L;           // 8M: bf16 x (dead after pointwise)
  short* Y   = base + 12582912L;           // 8M: aliases xb
  short* Qr  = base + 20971520L;           // 8M
  short* Kr  = base + 29360128L;           // 8M
  short* Vr  = base + 37748736L;           // 8M

  detect_dtype<<<1, 64, 0, stream>>>((const short*)x, flag);
  convert_x<<<4096, 256, 0, stream>>>(x, xb, flag);
  transpose_w<<<dim3(64, 64, 3), dim3(32, 8), 0, stream>>>(Wq, wt0, Wk, wtk, Wv, wtv, flag);
  gemm_bt<short><<<dim3(8, 16, 3), 512, 0, stream>>>(xb, wt0, wtk, wtv, Qr, Kr, Vr, 4096, 2048, 2048);
  transpose_w<<<dim3(64, 64, 1), dim3(32, 8), 0, stream>>>(Wp, wt0, Wp, wt0, Wp, wt0, flag);
  pointwise<<<dim3(4096), 256, 0, stream>>>(xb, ve, cosb, sinb, Wg, flag, Qr, Kr, Vr);
  transpose_v<<<dim3(64, 4, 32), dim3(32, 8), 0, stream>>>(Vr, Vt);
  flash<<<dim3(16, 32), 256, 0, stream>>>(Qr, Kr, Vt, Y);
  gemm_bt<float><<<dim3(8, 16, 1), 512, 0, stream>>>(Y, wt0, wt0, wt0, out, out, out, 4096, 2048, 2048);
}

// Round 3
// 469.906 us; speedup vs baseline: 1.0553x; 1.0553x over previous
//
#include <hip/hip_runtime.h>
#include <stdint.h>

typedef short bf16x8 __attribute__((ext_vector_type(8)));
typedef float f32x4 __attribute__((ext_vector_type(4)));

#define ASYNC16(g, l) __builtin_amdgcn_global_load_lds( \
    (const __attribute__((address_space(1))) unsigned int*)(g), \
    (__attribute__((address_space(3))) unsigned int*)(l), 16, 0, 0)

__device__ __forceinline__ float bf2f(short u) {
  union { unsigned int i; float f; } v;
  v.i = ((unsigned int)(unsigned short)u) << 16;
  return v.f;
}
__device__ __forceinline__ short f2bf(float f) {
  union { float f; unsigned int i; } v;
  v.f = f;
  return (short)(unsigned short)((v.i + 0x8000u) >> 16);
}
__device__ __forceinline__ float ldf(const void* p, long i, int isbf) {
  return isbf ? bf2f(((const short*)p)[i]) : ((const float*)p)[i];
}

// ---------------------------------------------------------------------------
__global__ void detect_dtype(const short* __restrict__ x, int* __restrict__ flag) {
  if (threadIdx.x == 0 && blockIdx.x == 0) {
    int cnt = 0;
    for (int i = 0; i < 128; ++i) {
      int e = (((unsigned short)x[i]) >> 7) & 0xFF;
      if (e >= 110 && e <= 136) ++cnt;
    }
    *flag = (cnt >= 120) ? 1 : 0;
  }
}

__global__ __launch_bounds__(256) void convert_x(
    const void* __restrict__ xin, short* __restrict__ xb, const int* __restrict__ flag) {
  long i = (long)blockIdx.x * 2048 + (long)threadIdx.x * 8;
  if (*flag) {
    *(bf16x8*)(xb + i) = *(const bf16x8*)((const short*)xin + i);
  } else {
    const float* xf = (const float*)xin;
    short tmp[8];
    #pragma unroll
    for (int j = 0; j < 8; ++j) tmp[j] = f2bf(xf[i + j]);
    *(bf16x8*)(xb + i) = *(bf16x8*)tmp;
  }
}

// ---------------------------------------------------------------------------
__global__ __launch_bounds__(256) void transpose_w(
    const void* __restrict__ S0, short* __restrict__ D0,
    const void* __restrict__ S1, short* __restrict__ D1,
    const void* __restrict__ S2, short* __restrict__ D2,
    const int* __restrict__ flag)
{
  int z = blockIdx.z;
  const void* S = (z == 0) ? S0 : (z == 1) ? S1 : S2;
  short* D = (z == 0) ? D0 : (z == 1) ? D1 : D2;
  int isbf = *flag;
  __shared__ short tile[32][33];
  int c0 = blockIdx.x * 32, r0 = blockIdx.y * 32;
  int tx = threadIdx.x, ty = threadIdx.y;
  #pragma unroll
  for (int i = 0; i < 4; ++i)
    tile[ty + 8*i][tx] = f2bf(ldf(S, (long)(r0 + ty + 8*i) * 2048 + c0 + tx, isbf));
  __syncthreads();
  #pragma unroll
  for (int i = 0; i < 4; ++i)
    D[(long)(c0 + ty + 8*i) * 2048 + r0 + tx] = tile[tx][ty + 8*i];
}

__global__ __launch_bounds__(256) void transpose_v(
    const short* __restrict__ Vr, short* __restrict__ Vt)
{
  __shared__ short tile[32][33];
  int bh = blockIdx.z;
  int b = bh >> 4, h = bh & 15;
  int t0 = blockIdx.x * 32, d0 = blockIdx.y * 32;
  int tx = threadIdx.x, ty = threadIdx.y;
  #pragma unroll
  for (int i = 0; i < 4; ++i)
    tile[ty + 8*i][tx] = Vr[(long)(b*2048 + t0 + ty + 8*i) * 2048 + h*128 + d0 + tx];
  __syncthreads();
  #pragma unroll
  for (int i = 0; i < 4; ++i)
    Vt[((long)bh * 128 + d0 + ty + 8*i) * 2048 + t0 + tx] = tile[tx][ty + 8*i];
}

// ---------------------------------------------------------------------------
// gemm_bt: proven R0 128x128-tile kernel (2 blocks/CU, ~845 TF). Used for
// the proj GEMM where its 512-block grid gives full CU coverage.
// ---------------------------------------------------------------------------
template<typename OutT>
__global__ __launch_bounds__(256) void gemm_bt(
    const short* __restrict__ A,
    const short* __restrict__ B0, const short* __restrict__ B1, const short* __restrict__ B2,
    OutT* __restrict__ C0, OutT* __restrict__ C1, OutT* __restrict__ C2,
    int M, int N, int K)
{
  int z = blockIdx.z;
  const short* Bt = (z == 0) ? B0 : (z == 1) ? B1 : B2;
  OutT* C = (z == 0) ? C0 : (z == 1) ? C1 : C2;

  int m0 = blockIdx.y * 128, n0 = blockIdx.x * 128;
  int tid = threadIdx.x;
  int lane = tid & 63, w = tid >> 6;
  int quad = lane >> 4, l16 = lane & 15;
  int wm = w >> 1, wn = w & 1;

  __shared__ short As[128][64];
  __shared__ short Bs[128][64];

  f32x4 zero4 = {0.f, 0.f, 0.f, 0.f};
  f32x4 acc[4][4];
  #pragma unroll
  for (int i = 0; i < 4; ++i)
    #pragma unroll
    for (int j = 0; j < 4; ++j) acc[i][j] = zero4;

  int r8 = lane >> 3;
  int srow = w * 32 + r8;
  int scol = ((lane & 7) ^ r8) * 8;

  for (int k0 = 0; k0 < K; k0 += 64) {
    #pragma unroll
    for (int i = 0; i < 4; ++i) {
      ASYNC16(A  + (long)(m0 + srow + i*8) * K + k0 + scol, &As[w*32 + i*8][0]);
      ASYNC16(Bt + (long)(n0 + srow + i*8) * K + k0 + scol, &Bs[w*32 + i*8][0]);
    }
    __syncthreads();
    #pragma unroll
    for (int kt = 0; kt < 2; ++kt) {
      int po = ((kt*4 + quad) ^ (l16 & 7)) * 8;
      bf16x8 af[4], bfr[4];
      #pragma unroll
      for (int i = 0; i < 4; ++i)
        af[i] = *(const bf16x8*)&As[wm*64 + i*16 + l16][po];
      #pragma unroll
      for (int j = 0; j < 4; ++j)
        bfr[j] = *(const bf16x8*)&Bs[wn*64 + j*16 + l16][po];
      #pragma unroll
      for (int i = 0; i < 4; ++i)
        #pragma unroll
        for (int j = 0; j < 4; ++j)
          acc[i][j] = __builtin_amdgcn_mfma_f32_16x16x32_bf16(af[i], bfr[j], acc[i][j], 0, 0, 0);
    }
    __syncthreads();
  }

  #pragma unroll
  for (int i = 0; i < 4; ++i)
    #pragma unroll
    for (int j = 0; j < 4; ++j) {
      int row = m0 + wm*64 + i*16 + quad*4;
      int col = n0 + wn*64 + j*16 + l16;
      #pragma unroll
      for (int r = 0; r < 4; ++r) {
        float v = acc[i][j][r];
        if constexpr (sizeof(OutT) == 4)
          C[(long)(row + r) * N + col] = v;
        else
          C[(long)(row + r) * N + col] = (OutT)f2bf(v);
      }
    }
}

// ---------------------------------------------------------------------------
// gemm256: 256x256 tile, BK=64, 8 waves (2M x 4N), wave tile 128x64.
// K-COLUMN granules (256 rows x 32 cols) enable counted vmcnt:
//   phases 0-1 consume kt0 granules, 2-3 consume kt1; phase p stages
//   granule #p of tile t+1 (2 x global_load_lds). Use-stage distance
//   3-4 phases; waits are vmcnt(4) at end of ph1/ph3 (forces granules
//   staged >=2 phases ago, keeps last 2 granules in flight). Never
//   drains to 0 in steady state (m218: counted vs drain0 = +38-73%).
// Granule LDS layout: [128 lines][8 octets x 8 shorts]; line L holds rows
// 2L,2L+1 with phys_oct = log_oct ^ (L&7) folded into the per-lane global
// source (linear gload_lds dest). Reads: line = r>>1,
// phys = ((r&1)*4 + quad) ^ (l16>>1) -> 2 lanes/octet = conflict-free.
// ---------------------------------------------------------------------------
template<typename OutT>
__global__ __launch_bounds__(512, 2) void gemm256(
    const short* __restrict__ A,
    const short* __restrict__ B0, const short* __restrict__ B1, const short* __restrict__ B2,
    OutT* __restrict__ C0, OutT* __restrict__ C1, OutT* __restrict__ C2,
    int M, int N, int K)
{
  int z = blockIdx.z;
  const short* Bt = (z == 0) ? B0 : (z == 1) ? B1 : B2;
  OutT* C = (z == 0) ? C0 : (z == 1) ? C1 : C2;

  int m0 = blockIdx.y * 256, n0 = blockIdx.x * 256;
  int tid = threadIdx.x;
  int lane = tid & 63, w = tid >> 6;
  int quad = lane >> 4, l16 = lane & 15;
  int wm = w >> 2, wn = w & 3;

  __shared__ short Ag[2][2][128*64];   // 64 KB  [dbuf][kt][line*64+col]
  __shared__ short Bg[2][2][128*64];   // 64 KB

  f32x4 zero4 = {0.f, 0.f, 0.f, 0.f};
  f32x4 acc[8][4];
  #pragma unroll
  for (int i = 0; i < 8; ++i)
    #pragma unroll
    for (int j = 0; j < 4; ++j) acc[i][j] = zero4;

  // ---- stage lane constants (swizzle on the global side) ----
  // lane writes LDS line (w*8 + l8) [+ i*64], phys oct o; that slot holds
  // logical oct lo = o ^ l8 -> row 2*line + (lo>>2), col-oct lo&3.
  int l8 = lane >> 3, o = lane & 7, lo = o ^ l8;
  int rowb = w*16 + 2*l8 + (lo >> 2);          // + i*128
  int colb = (lo & 3) * 8;                     // + k0 + kt*32
  const short* Ab = A  + (long)(m0 + rowb) * K + colb;
  const short* Bb = Bt + (long)(n0 + rowb) * K + colb;

  // ---- ds_read lane constants ----
  int hl = l16 >> 1;
  int phys = ((((l16 & 1) << 2) + quad) ^ hl) * 8;
  int rdA = (wm*64 + hl)*64 + phys;            // + mf*512 (shorts)
  int rdB = (wn*32 + hl)*64 + phys;            // + nf*512

  int NT = K >> 6;

  // prologue: stage tile 0's 4 granules (A0,B0,A1,B1), keep last 2 in flight
  ASYNC16(Ab,             &Ag[0][0][(w*8)*64]);
  ASYNC16(Ab + 128L*K,    &Ag[0][0][(64 + w*8)*64]);
  ASYNC16(Bb,             &Bg[0][0][(w*8)*64]);
  ASYNC16(Bb + 128L*K,    &Bg[0][0][(64 + w*8)*64]);
  ASYNC16(Ab + 32,        &Ag[0][1][(w*8)*64]);
  ASYNC16(Ab + 32 + 128L*K, &Ag[0][1][(64 + w*8)*64]);
  ASYNC16(Bb + 32,        &Bg[0][1][(w*8)*64]);
  ASYNC16(Bb + 32 + 128L*K, &Bg[0][1][(64 + w*8)*64]);
  asm volatile("s_waitcnt vmcnt(4)" ::: "memory");
  __builtin_amdgcn_s_barrier();

  bf16x8 am[8], b0, b1;

  for (int t = 0; t < NT; ++t) {
    int db = t & 1, sdb = db ^ 1;
    long kn = (long)(t + 1) * 64;
    bool st = (t + 1 < NT);

    // ---- ph0: read A-kt0 (8) + B-kt0 nf0,1 (2); stage A(t+1,kt0)
    #pragma unroll
    for (int mf = 0; mf < 8; ++mf)
      am[mf] = *(const bf16x8*)&Ag[db][0][rdA + mf*512];
    b0 = *(const bf16x8*)&Bg[db][0][rdB];
    b1 = *(const bf16x8*)&Bg[db][0][rdB + 512];
    if (st) {
      ASYNC16(Ab + kn,            &Ag[sdb][0][(w*8)*64]);
      ASYNC16(Ab + kn + 128L*K,   &Ag[sdb][0][(64 + w*8)*64]);
    }
    __builtin_amdgcn_s_barrier();
    __builtin_amdgcn_s_setprio(1);
    #pragma unroll
    for (int mf = 0; mf < 8; ++mf)
      acc[mf][0] = __builtin_amdgcn_mfma_f32_16x16x32_bf16(am[mf], b0, acc[mf][0], 0, 0, 0);
    #pragma unroll
    for (int mf = 0; mf < 8; ++mf)
      acc[mf][1] = __builtin_amdgcn_mfma_f32_16x16x32_bf16(am[mf], b1, acc[mf][1], 0, 0, 0);
    __builtin_amdgcn_s_setprio(0);
    __builtin_amdgcn_s_barrier();

    // ---- ph1: read B-kt0 nf2,3; stage B(t+1,kt0); wait vmcnt(4)
    b0 = *(const bf16x8*)&Bg[db][0][rdB + 2*512];
    b1 = *(const bf16x8*)&Bg[db][0][rdB + 3*512];
    if (st) {
      ASYNC16(Bb + kn,            &Bg[sdb][0][(w*8)*64]);
      ASYNC16(Bb + kn + 128L*K,   &Bg[sdb][0][(64 + w*8)*64]);
    }
    __builtin_amdgcn_s_barrier();
    __builtin_amdgcn_s_setprio(1);
    #pragma unroll
    for (int mf = 0; mf < 8; ++mf)
      acc[mf][2] = __builtin_amdgcn_mfma_f32_16x16x32_bf16(am[mf], b0, acc[mf][2], 0, 0, 0);
    #pragma unroll
    for (int mf = 0; mf < 8; ++mf)
      acc[mf][3] = __builtin_amdgcn_mfma_f32_16x16x32_bf16(am[mf], b1, acc[mf][3], 0, 0, 0);
    __builtin_amdgcn_s_setprio(0);
    if (st) asm volatile("s_waitcnt vmcnt(4)" ::: "memory");
    else    asm volatile("s_waitcnt vmcnt(0)" ::: "memory");
    __builtin_amdgcn_s_barrier();

    // ---- ph2: read A-kt1 (8) + B-kt1 nf0,1; stage A(t+1,kt1)
    #pragma unroll
    for (int mf = 0; mf < 8; ++mf)
      am[mf] = *(const bf16x8*)&Ag[db][1][rdA + mf*512];
    b0 = *(const bf16x8*)&Bg[db][1][rdB];
    b1 = *(const bf16x8*)&Bg[db][1][rdB + 512];
    if (st) {
      ASYNC16(Ab + kn + 32,          &Ag[sdb][1][(w*8)*64]);
      ASYNC16(Ab + kn + 32 + 128L*K, &Ag[sdb][1][(64 + w*8)*64]);
    }
    __builtin_amdgcn_s_barrier();
    __builtin_amdgcn_s_setprio(1);
    #pragma unroll
    for (int mf = 0; mf < 8; ++mf)
      acc[mf][0] = __builtin_amdgcn_mfma_f32_16x16x32_bf16(am[mf], b0, acc[mf][0], 0, 0, 0);
    #pragma unroll
    for (int mf = 0; mf < 8; ++mf)
      acc[mf][1] = __builtin_amdgcn_mfma_f32_16x16x32_bf16(am[mf], b1, acc[mf][1], 0, 0, 0);
    __builtin_amdgcn_s_setprio(0);
    __builtin_amdgcn_s_barrier();

    // ---- ph3: read B-kt1 nf2,3; stage B(t+1,kt1); wait vmcnt(4)
    b0 = *(const bf16x8*)&Bg[db][1][rdB + 2*512];
    b1 = *(const bf16x8*)&Bg[db][1][rdB + 3*512];
    if (st) {
      ASYNC16(Bb + kn + 32,          &Bg[sdb][1][(w*8)*64]);
      ASYNC16(Bb + kn + 32 + 128L*K, &Bg[sdb][1][(64 + w*8)*64]);
    }
    __builtin_amdgcn_s_barrier();
    __builtin_amdgcn_s_setprio(1);
    #pragma unroll
    for (int mf = 0; mf < 8; ++mf)
      acc[mf][2] = __builtin_amdgcn_mfma_f32_16x16x32_bf16(am[mf], b0, acc[mf][2], 0, 0, 0);
    #pragma unroll
    for (int mf = 0; mf < 8; ++mf)
      acc[mf][3] = __builtin_amdgcn_mfma_f32_16x16x32_bf16(am[mf], b1, acc[mf][3], 0, 0, 0);
    __builtin_amdgcn_s_setprio(0);
    if (st) {
      asm volatile("s_waitcnt vmcnt(4)" ::: "memory");
      __builtin_amdgcn_s_barrier();
    }
  }

  #pragma unroll
  for (int mf = 0; mf < 8; ++mf)
    #pragma unroll
    for (int nf = 0; nf < 4; ++nf) {
      int row = m0 + wm*128 + mf*16 + quad*4;
      int col = n0 + wn*64 + nf*16 + l16;
      #pragma unroll
      for (int r = 0; r < 4; ++r) {
        float v = acc[mf][nf][r];
        if constexpr (sizeof(OutT) == 4)
          C[(long)(row + r) * N + col] = v;
        else
          C[(long)(row + r) * N + col] = (OutT)f2bf(v);
      }
    }
}

// ---------------------------------------------------------------------------
__global__ __launch_bounds__(256) void pointwise(
    const short* __restrict__ xb, const void* __restrict__ ve,
    const void* __restrict__ cosb, const void* __restrict__ sinb,
    const void* __restrict__ Wg, const int* __restrict__ flag,
    short* __restrict__ Qr, short* __restrict__ Kr, short* __restrict__ Vr)
{
  int row = blockIdx.x;
  int tid = threadIdx.x;
  int isbf = *flag;
  __shared__ float xg[32];
  __shared__ float gates[16];
  if (tid < 32) xg[tid] = bf2f(xb[(long)row * 2048 + tid]);
  __syncthreads();
  if (tid < 16) {
    float g = 0.f;
    #pragma unroll
    for (int i = 0; i < 32; ++i) g += xg[i] * ldf(Wg, i*16 + tid, isbf);
    gates[tid] = 2.0f / (1.0f + __expf(-g));
  }
  __syncthreads();
  {
    // vectorized gate update: each thread handles 8 contiguous channels
    int idx = tid * 8;
    int h = idx >> 7;
    long p = (long)row * 2048 + idx;
    float g = gates[h];
    bf16x8 vv = *(bf16x8*)(Vr + p);
    short tmp[8];
    if (isbf) {
      bf16x8 vb = *(const bf16x8*)((const short*)ve + p);
      #pragma unroll
      for (int j = 0; j < 8; ++j) tmp[j] = f2bf(bf2f(vv[j]) + g * bf2f(vb[j]));
    } else {
      const float* vf = (const float*)ve;
      f32x4 a = *(const f32x4*)(vf + p);
      f32x4 b2 = *(const f32x4*)(vf + p + 4);
      #pragma unroll
      for (int j = 0; j < 4; ++j) tmp[j]     = f2bf(bf2f(vv[j])     + g * a[j]);
      #pragma unroll
      for (int j = 0; j < 4; ++j) tmp[j + 4] = f2bf(bf2f(vv[j + 4]) + g * b2[j]);
    }
    *(bf16x8*)(Vr + p) = *(bf16x8*)tmp;
  }
  int lane = tid & 63, w = tid >> 6;
  int t = row & 2047;
  #pragma unroll
  for (int it = 0; it < 8; ++it) {
    int unit = it * 4 + w;
    short* P = (unit < 16) ? Qr : Kr;
    int h = unit & 15;
    long base = (long)row * 2048 + h * 128;
    float x1 = bf2f(P[base + lane]);
    float x2 = bf2f(P[base + lane + 64]);
    float c = ldf(cosb, t*64 + lane, isbf);
    float s = ldf(sinb, t*64 + lane, isbf);
    float r1 = x1 * c + x2 * s;
    float r2 = -x1 * s + x2 * c;
    float ss = r1*r1 + r2*r2;
    #pragma unroll
    for (int off = 32; off; off >>= 1) ss += __shfl_xor(ss, off);
    float rn = rsqrtf(ss * (1.0f/128.0f) + 1e-6f);
    P[base + lane]      = f2bf(r1 * rn);
    P[base + lane + 64] = f2bf(r2 * rn);
  }
}

// ---------------------------------------------------------------------------
// Flash v3 (+ T5 setprio around MFMA clusters)
// ---------------------------------------------------------------------------
#define FL_C1 0.12751741f
#define FL_C2 16.321698f

__global__ __launch_bounds__(256) void flash(
    const short* __restrict__ Q, const short* __restrict__ K,
    const short* __restrict__ Vt, short* __restrict__ Y)
{
  int bx = blockIdx.x;
  int bh = blockIdx.y;
  int b = bh >> 4, h = bh & 15;
  int tid = threadIdx.x;
  int lane = tid & 63, w = tid >> 6;
  int quad = lane >> 4, l16 = lane & 15;

  __shared__ short Ks[2][64*128];
  __shared__ short Vts[2][128*64];
  __shared__ short Ps[4][16*72];

  int qtA = bx, qtB = 31 - bx;
  int nA = qtA + 1, nB = qtB + 1;
  int total = nA + nB;

  int kkey = tid >> 4;
  int klo  = (tid & 15) ^ (kkey & 7);
  int vd   = tid >> 3;
  int vlo  = (tid & 7) ^ (vd & 7);
  const short* Kbase = K + (long)(b*2048 + kkey) * 2048 + h*128 + klo*8;
  const short* Vbase = Vt + ((long)bh*128 + vd) * 2048 + vlo*8;

  f32x4 zero4 = {0.f, 0.f, 0.f, 0.f};
  f32x4 o[8];
  float l_i[4];
  bf16x8 qf[4];
  bf16x8 ones;
  #pragma unroll
  for (int j = 0; j < 8; ++j) ones[j] = (short)0x3F80;

  auto stage = [&](int tt, int bufp) {
    int tl = (tt < nA) ? tt : tt - nA;
    long ko = (long)tl * 64 * 2048;
    int  vo = tl * 64;
    #pragma unroll
    for (int i = 0; i < 4; ++i)
      ASYNC16(Kbase + ko + (long)i*16*2048, &Ks[bufp][(i*16 + w*4)*128]);
    #pragma unroll
    for (int i = 0; i < 4; ++i)
      ASYNC16(Vbase + vo + (long)i*32*2048, &Vts[bufp][(i*32 + w*8)*64]);
  };
  auto loadQ = [&](int qt) {
    const short* Qb = Q + (long)(b*2048 + qt*64 + w*16 + l16) * 2048 + h*128;
    #pragma unroll
    for (int kt = 0; kt < 4; ++kt)
      qf[kt] = *(const bf16x8*)(Qb + kt*32 + quad*8);
  };
  auto flushO = [&](int qt) {
    #pragma unroll
    for (int r = 0; r < 4; ++r) {
      float inv = 1.0f / fmaxf(l_i[r], 1e-30f);
      short* yp = Y + (long)(b*2048 + qt*64 + w*16 + quad*4 + r) * 2048 + h*128;
      #pragma unroll
      for (int c8 = 0; c8 < 8; ++c8)
        yp[c8*16 + l16] = f2bf(o[c8][r] * inv);
    }
  };

  #pragma unroll
  for (int c = 0; c < 8; ++c) o[c] = zero4;
  #pragma unroll
  for (int r = 0; r < 4; ++r) l_i[r] = 0.f;
  loadQ(qtA);
  stage(0, 0);

  int qt = qtA, n_seg = nA, segbase = 0;
  for (int tt = 0; tt < total; ++tt) {
    int buf = tt & 1;
    asm volatile("s_waitcnt vmcnt(0)" ::: "memory");
    __builtin_amdgcn_s_barrier();
    if (tt + 1 < total) stage(tt + 1, buf ^ 1);
    if (tt == nA) {
      flushO(qtA);
      loadQ(qtB);
      #pragma unroll
      for (int c = 0; c < 8; ++c) o[c] = zero4;
      #pragma unroll
      for (int r = 0; r < 4; ++r) l_i[r] = 0.f;
      qt = qtB; n_seg = nB; segbase = nA;
    }
    int tloc = tt - segbase;
    int kv0 = tloc * 64;

    // S = Q K^T
    f32x4 s[4];
    __builtin_amdgcn_s_setprio(1);
    #pragma unroll
    for (int c = 0; c < 4; ++c) {
      f32x4 acc = zero4;
      #pragma unroll
      for (int kt = 0; kt < 4; ++kt) {
        int po = ((kt*4 + quad) ^ (l16 & 7)) * 8;
        bf16x8 kf = *(const bf16x8*)&Ks[buf][(c*16 + l16)*128 + po];
        acc = __builtin_amdgcn_mfma_f32_16x16x32_bf16(qf[kt], kf, acc, 0, 0, 0);
      }
      s[c] = acc;
    }
    __builtin_amdgcn_s_setprio(0);

    bool domask = (tloc == n_seg - 1);
    int qgb = qt*64 + w*16 + quad*4;
    #pragma unroll
    for (int c = 0; c < 4; ++c) {
      int kg = kv0 + c*16 + l16;
      #pragma unroll
      for (int r = 0; r < 4; ++r) {
        float t = s[c][r] * FL_C1 - FL_C2;
        if (domask && kg > qgb + r) t = -1000.0f;
        float pv = exp2f(t);
        Ps[w][(quad*4 + r)*72 + c*16 + l16] = f2bf(pv);
      }
    }
    asm volatile("s_waitcnt lgkmcnt(0)" ::: "memory");
    bf16x8 pa0 = *(const bf16x8*)&Ps[w][l16*72 + quad*8];
    bf16x8 pa1 = *(const bf16x8*)&Ps[w][l16*72 + 32 + quad*8];

    __builtin_amdgcn_s_setprio(1);
    f32x4 racc = __builtin_amdgcn_mfma_f32_16x16x32_bf16(pa0, ones, zero4, 0, 0, 0);
    racc = __builtin_amdgcn_mfma_f32_16x16x32_bf16(pa1, ones, racc, 0, 0, 0);
    #pragma unroll
    for (int r = 0; r < 4; ++r) l_i[r] += racc[r];

    #pragma unroll
    for (int c8 = 0; c8 < 8; ++c8) {
      int po0 = ((0*4 + quad) ^ (l16 & 7)) * 8;
      int po1 = ((1*4 + quad) ^ (l16 & 7)) * 8;
      bf16x8 v0 = *(const bf16x8*)&Vts[buf][(c8*16 + l16)*64 + po0];
      bf16x8 v1 = *(const bf16x8*)&Vts[buf][(c8*16 + l16)*64 + po1];
      o[c8] = __builtin_amdgcn_mfma_f32_16x16x32_bf16(pa0, v0, o[c8], 0, 0, 0);
      o[c8] = __builtin_amdgcn_mfma_f32_16x16x32_bf16(pa1, v1, o[c8], 0, 0, 0);
    }
    __builtin_amdgcn_s_setprio(0);
  }
  flushO(qtB);
}

// ---------------------------------------------------------------------------
extern "C" void kernel_launch(void* const* d_in, const int* in_sizes, int n_in,
                              void* d_out, int out_size, void* d_ws, size_t ws_size,
                              hipStream_t stream) {
  const void* x    = d_in[0];
  const void* ve   = d_in[1];
  const void* cosb = d_in[2];
  const void* sinb = d_in[3];
  const void* Wq   = d_in[4];
  const void* Wk   = d_in[5];
  const void* Wv   = d_in[6];
  const void* Wg   = d_in[7];
  const void* Wp   = d_in[8];
  float* out = (float*)d_out;

  int*   flag = (int*)d_ws;
  short* base = (short*)d_ws + 256;
  short* wt0 = base;                       // 4M: Wq^T, then Wp^T
  short* wtk = base + 4194304L;            // 4M: Wk^T (dead after QKV gemm)
  short* wtv = base + 8388608L;            // 4M: Wv^T (dead after QKV gemm)
  short* Vt  = base + 4194304L;            // 8M: aliases wtk+wtv
  short* xb  = base + 12582912L;           // 8M: bf16 x (dead after pointwise)
  short* Y   = base + 12582912L;           // 8M: aliases xb
  short* Qr  = base + 20971520L;           // 8M
  short* Kr  = base + 29360128L;           // 8M
  short* Vr  = base + 37748736L;           // 8M

  detect_dtype<<<1, 64, 0, stream>>>((const short*)x, flag);
  convert_x<<<4096, 256, 0, stream>>>(x, xb, flag);
  transpose_w<<<dim3(64, 64, 3), dim3(32, 8), 0, stream>>>(Wq, wt0, Wk, wtk, Wv, wtv, flag);
  gemm256<short><<<dim3(8, 16, 3), 512, 0, stream>>>(xb, wt0, wtk, wtv, Qr, Kr, Vr, 4096, 2048, 2048);
  transpose_w<<<dim3(64, 64, 1), dim3(32, 8), 0, stream>>>(Wp, wt0, Wp, wt0, Wp, wt0, flag);
  pointwise<<<dim3(4096), 256, 0, stream>>>(xb, ve, cosb, sinb, Wg, flag, Qr, Kr, Vr);
  transpose_v<<<dim3(64, 4, 32), dim3(32, 8), 0, stream>>>(Vr, Vt);
  flash<<<dim3(16, 32), 256, 0, stream>>>(Qr, Kr, Vt, Y);
  gemm_bt<float><<<dim3(16, 32, 1), 256, 0, stream>>>(Y, wt0, wt0, wt0, out, out, out, 4096, 2048, 2048);
}

// Round 4
// 456.714 us; speedup vs baseline: 1.0858x; 1.0289x over previous
//
#include <hip/hip_runtime.h>
#include <stdint.h>

typedef short bf16x8 __attribute__((ext_vector_type(8)));
typedef float f32x4 __attribute__((ext_vector_type(4)));

#define ASYNC16(g, l) __builtin_amdgcn_global_load_lds( \
    (const __attribute__((address_space(1))) unsigned int*)(g), \
    (__attribute__((address_space(3))) unsigned int*)(l), 16, 0, 0)

__device__ __forceinline__ float bf2f(short u) {
  union { unsigned int i; float f; } v;
  v.i = ((unsigned int)(unsigned short)u) << 16;
  return v.f;
}
__device__ __forceinline__ short f2bf(float f) {
  union { float f; unsigned int i; } v;
  v.f = f;
  return (short)(unsigned short)((v.i + 0x8000u) >> 16);
}
__device__ __forceinline__ float ldf(const void* p, long i, int isbf) {
  return isbf ? bf2f(((const short*)p)[i]) : ((const float*)p)[i];
}

// ---------------------------------------------------------------------------
__global__ void detect_dtype(const short* __restrict__ x, int* __restrict__ flag) {
  if (threadIdx.x == 0 && blockIdx.x == 0) {
    int cnt = 0;
    for (int i = 0; i < 128; ++i) {
      int e = (((unsigned short)x[i]) >> 7) & 0xFF;
      if (e >= 110 && e <= 136) ++cnt;
    }
    *flag = (cnt >= 120) ? 1 : 0;
  }
}

__global__ __launch_bounds__(256) void convert_x(
    const void* __restrict__ xin, short* __restrict__ xb, const int* __restrict__ flag) {
  long i = (long)blockIdx.x * 2048 + (long)threadIdx.x * 8;
  if (*flag) {
    *(bf16x8*)(xb + i) = *(const bf16x8*)((const short*)xin + i);
  } else {
    const float* xf = (const float*)xin;
    short tmp[8];
    #pragma unroll
    for (int j = 0; j < 8; ++j) tmp[j] = f2bf(xf[i + j]);
    *(bf16x8*)(xb + i) = *(bf16x8*)tmp;
  }
}

// ---------------------------------------------------------------------------
__global__ __launch_bounds__(256) void transpose_w(
    const void* __restrict__ S0, short* __restrict__ D0,
    const void* __restrict__ S1, short* __restrict__ D1,
    const void* __restrict__ S2, short* __restrict__ D2,
    const int* __restrict__ flag)
{
  int z = blockIdx.z;
  const void* S = (z == 0) ? S0 : (z == 1) ? S1 : S2;
  short* D = (z == 0) ? D0 : (z == 1) ? D1 : D2;
  int isbf = *flag;
  __shared__ short tile[32][33];
  int c0 = blockIdx.x * 32, r0 = blockIdx.y * 32;
  int tx = threadIdx.x, ty = threadIdx.y;
  #pragma unroll
  for (int i = 0; i < 4; ++i)
    tile[ty + 8*i][tx] = f2bf(ldf(S, (long)(r0 + ty + 8*i) * 2048 + c0 + tx, isbf));
  __syncthreads();
  #pragma unroll
  for (int i = 0; i < 4; ++i)
    D[(long)(c0 + ty + 8*i) * 2048 + r0 + tx] = tile[tx][ty + 8*i];
}

__global__ __launch_bounds__(256) void transpose_v(
    const short* __restrict__ Vr, short* __restrict__ Vt)
{
  __shared__ short tile[32][33];
  int bh = blockIdx.z;
  int b = bh >> 4, h = bh & 15;
  int t0 = blockIdx.x * 32, d0 = blockIdx.y * 32;
  int tx = threadIdx.x, ty = threadIdx.y;
  #pragma unroll
  for (int i = 0; i < 4; ++i)
    tile[ty + 8*i][tx] = Vr[(long)(b*2048 + t0 + ty + 8*i) * 2048 + h*128 + d0 + tx];
  __syncthreads();
  #pragma unroll
  for (int i = 0; i < 4; ++i)
    Vt[((long)bh * 128 + d0 + ty + 8*i) * 2048 + t0 + tx] = tile[tx][ty + 8*i];
}

// ---------------------------------------------------------------------------
// gemm_bt: proven R0 128x128-tile kernel (~845 TF, implicit multi-block/CU
// overlap).  NEW: T1 XCD-aware block swizzle — dispatch-linear id d maps to
// XCD d%8 (measured round-robin); we give each XCD an 8x8 chunk of the
// 16x32 grid so its L2 holds A-panel (4 MB) + B-panel (4 MB) instead of
// the fully-spread default.  Bijective for the 512-block grid.
// ---------------------------------------------------------------------------
template<typename OutT>
__global__ __launch_bounds__(256) void gemm_bt(
    const short* __restrict__ A,
    const short* __restrict__ B0, const short* __restrict__ B1, const short* __restrict__ B2,
    OutT* __restrict__ C0, OutT* __restrict__ C1, OutT* __restrict__ C2,
    int M, int N, int K)
{
  int z = blockIdx.z;
  const short* Bt = (z == 0) ? B0 : (z == 1) ? B1 : B2;
  OutT* C = (z == 0) ? C0 : (z == 1) ? C1 : C2;

  // XCD swizzle: d%8 = XCD; chunk = 8x8 blocks (1024 rows x 1024 cols)
  int d = blockIdx.y * 16 + blockIdx.x;
  int xcd = d & 7, ci = d >> 3;
  int bx = (xcd & 1) * 8 + (ci & 7);
  int by = (xcd >> 1) * 8 + (ci >> 3);
  int m0 = by * 128, n0 = bx * 128;

  int tid = threadIdx.x;
  int lane = tid & 63, w = tid >> 6;
  int quad = lane >> 4, l16 = lane & 15;
  int wm = w >> 1, wn = w & 1;

  __shared__ short As[128][64];
  __shared__ short Bs[128][64];

  f32x4 zero4 = {0.f, 0.f, 0.f, 0.f};
  f32x4 acc[4][4];
  #pragma unroll
  for (int i = 0; i < 4; ++i)
    #pragma unroll
    for (int j = 0; j < 4; ++j) acc[i][j] = zero4;

  int r8 = lane >> 3;
  int srow = w * 32 + r8;
  int scol = ((lane & 7) ^ r8) * 8;

  for (int k0 = 0; k0 < K; k0 += 64) {
    #pragma unroll
    for (int i = 0; i < 4; ++i) {
      ASYNC16(A  + (long)(m0 + srow + i*8) * K + k0 + scol, &As[w*32 + i*8][0]);
      ASYNC16(Bt + (long)(n0 + srow + i*8) * K + k0 + scol, &Bs[w*32 + i*8][0]);
    }
    __syncthreads();
    #pragma unroll
    for (int kt = 0; kt < 2; ++kt) {
      int po = ((kt*4 + quad) ^ (l16 & 7)) * 8;
      bf16x8 af[4], bfr[4];
      #pragma unroll
      for (int i = 0; i < 4; ++i)
        af[i] = *(const bf16x8*)&As[wm*64 + i*16 + l16][po];
      #pragma unroll
      for (int j = 0; j < 4; ++j)
        bfr[j] = *(const bf16x8*)&Bs[wn*64 + j*16 + l16][po];
      #pragma unroll
      for (int i = 0; i < 4; ++i)
        #pragma unroll
        for (int j = 0; j < 4; ++j)
          acc[i][j] = __builtin_amdgcn_mfma_f32_16x16x32_bf16(af[i], bfr[j], acc[i][j], 0, 0, 0);
    }
    __syncthreads();
  }

  #pragma unroll
  for (int i = 0; i < 4; ++i)
    #pragma unroll
    for (int j = 0; j < 4; ++j) {
      int row = m0 + wm*64 + i*16 + quad*4;
      int col = n0 + wn*64 + j*16 + l16;
      #pragma unroll
      for (int r = 0; r < 4; ++r) {
        float v = acc[i][j][r];
        if constexpr (sizeof(OutT) == 4)
          C[(long)(row + r) * N + col] = v;
        else
          C[(long)(row + r) * N + col] = (OutT)f2bf(v);
      }
    }
}

// ---------------------------------------------------------------------------
__global__ __launch_bounds__(256) void pointwise(
    const short* __restrict__ xb, const void* __restrict__ ve,
    const void* __restrict__ cosb, const void* __restrict__ sinb,
    const void* __restrict__ Wg, const int* __restrict__ flag,
    short* __restrict__ Qr, short* __restrict__ Kr, short* __restrict__ Vr)
{
  int row = blockIdx.x;
  int tid = threadIdx.x;
  int isbf = *flag;
  __shared__ float xg[32];
  __shared__ float gates[16];
  if (tid < 32) xg[tid] = bf2f(xb[(long)row * 2048 + tid]);
  __syncthreads();
  if (tid < 16) {
    float g = 0.f;
    #pragma unroll
    for (int i = 0; i < 32; ++i) g += xg[i] * ldf(Wg, i*16 + tid, isbf);
    gates[tid] = 2.0f / (1.0f + __expf(-g));
  }
  __syncthreads();
  {
    // vectorized gate update: each thread handles 8 contiguous channels
    int idx = tid * 8;
    int h = idx >> 7;
    long p = (long)row * 2048 + idx;
    float g = gates[h];
    bf16x8 vv = *(bf16x8*)(Vr + p);
    short tmp[8];
    if (isbf) {
      bf16x8 vb = *(const bf16x8*)((const short*)ve + p);
      #pragma unroll
      for (int j = 0; j < 8; ++j) tmp[j] = f2bf(bf2f(vv[j]) + g * bf2f(vb[j]));
    } else {
      const float* vf = (const float*)ve;
      f32x4 a = *(const f32x4*)(vf + p);
      f32x4 b2 = *(const f32x4*)(vf + p + 4);
      #pragma unroll
      for (int j = 0; j < 4; ++j) tmp[j]     = f2bf(bf2f(vv[j])     + g * a[j]);
      #pragma unroll
      for (int j = 0; j < 4; ++j) tmp[j + 4] = f2bf(bf2f(vv[j + 4]) + g * b2[j]);
    }
    *(bf16x8*)(Vr + p) = *(bf16x8*)tmp;
  }
  int lane = tid & 63, w = tid >> 6;
  int t = row & 2047;
  #pragma unroll
  for (int it = 0; it < 8; ++it) {
    int unit = it * 4 + w;
    short* P = (unit < 16) ? Qr : Kr;
    int h = unit & 15;
    long base = (long)row * 2048 + h * 128;
    float x1 = bf2f(P[base + lane]);
    float x2 = bf2f(P[base + lane + 64]);
    float c = ldf(cosb, t*64 + lane, isbf);
    float s = ldf(sinb, t*64 + lane, isbf);
    float r1 = x1 * c + x2 * s;
    float r2 = -x1 * s + x2 * c;
    float ss = r1*r1 + r2*r2;
    #pragma unroll
    for (int off = 32; off; off >>= 1) ss += __shfl_xor(ss, off);
    float rn = rsqrtf(ss * (1.0f/128.0f) + 1e-6f);
    P[base + lane]      = f2bf(r1 * rn);
    P[base + lane + 64] = f2bf(r2 * rn);
  }
}

// ---------------------------------------------------------------------------
// Flash v3 (+ T5 setprio) + T1 XCD swizzle: 4 consecutive (b,h) per XCD so
// each XCD's L2 holds exactly its 4 MB of K/V.
// ---------------------------------------------------------------------------
#define FL_C1 0.12751741f
#define FL_C2 16.321698f

__global__ __launch_bounds__(256) void flash(
    const short* __restrict__ Q, const short* __restrict__ K,
    const short* __restrict__ Vt, short* __restrict__ Y)
{
  int d = blockIdx.y * 16 + blockIdx.x;
  int xcd = d & 7, ci = d >> 3;
  int bx = ci & 15;
  int bh = xcd * 4 + (ci >> 4);
  int b = bh >> 4, h = bh & 15;
  int tid = threadIdx.x;
  int lane = tid & 63, w = tid >> 6;
  int quad = lane >> 4, l16 = lane & 15;

  __shared__ short Ks[2][64*128];
  __shared__ short Vts[2][128*64];
  __shared__ short Ps[4][16*72];

  int qtA = bx, qtB = 31 - bx;
  int nA = qtA + 1, nB = qtB + 1;
  int total = nA + nB;

  int kkey = tid >> 4;
  int klo  = (tid & 15) ^ (kkey & 7);
  int vd   = tid >> 3;
  int vlo  = (tid & 7) ^ (vd & 7);
  const short* Kbase = K + (long)(b*2048 + kkey) * 2048 + h*128 + klo*8;
  const short* Vbase = Vt + ((long)bh*128 + vd) * 2048 + vlo*8;

  f32x4 zero4 = {0.f, 0.f, 0.f, 0.f};
  f32x4 o[8];
  float l_i[4];
  bf16x8 qf[4];
  bf16x8 ones;
  #pragma unroll
  for (int j = 0; j < 8; ++j) ones[j] = (short)0x3F80;

  auto stage = [&](int tt, int bufp) {
    int tl = (tt < nA) ? tt : tt - nA;
    long ko = (long)tl * 64 * 2048;
    int  vo = tl * 64;
    #pragma unroll
    for (int i = 0; i < 4; ++i)
      ASYNC16(Kbase + ko + (long)i*16*2048, &Ks[bufp][(i*16 + w*4)*128]);
    #pragma unroll
    for (int i = 0; i < 4; ++i)
      ASYNC16(Vbase + vo + (long)i*32*2048, &Vts[bufp][(i*32 + w*8)*64]);
  };
  auto loadQ = [&](int qt) {
    const short* Qb = Q + (long)(b*2048 + qt*64 + w*16 + l16) * 2048 + h*128;
    #pragma unroll
    for (int kt = 0; kt < 4; ++kt)
      qf[kt] = *(const bf16x8*)(Qb + kt*32 + quad*8);
  };
  auto flushO = [&](int qt) {
    #pragma unroll
    for (int r = 0; r < 4; ++r) {
      float inv = 1.0f / fmaxf(l_i[r], 1e-30f);
      short* yp = Y + (long)(b*2048 + qt*64 + w*16 + quad*4 + r) * 2048 + h*128;
      #pragma unroll
      for (int c8 = 0; c8 < 8; ++c8)
        yp[c8*16 + l16] = f2bf(o[c8][r] * inv);
    }
  };

  #pragma unroll
  for (int c = 0; c < 8; ++c) o[c] = zero4;
  #pragma unroll
  for (int r = 0; r < 4; ++r) l_i[r] = 0.f;
  loadQ(qtA);
  stage(0, 0);

  int qt = qtA, n_seg = nA, segbase = 0;
  for (int tt = 0; tt < total; ++tt) {
    int buf = tt & 1;
    asm volatile("s_waitcnt vmcnt(0)" ::: "memory");
    __builtin_amdgcn_s_barrier();
    if (tt + 1 < total) stage(tt + 1, buf ^ 1);
    if (tt == nA) {
      flushO(qtA);
      loadQ(qtB);
      #pragma unroll
      for (int c = 0; c < 8; ++c) o[c] = zero4;
      #pragma unroll
      for (int r = 0; r < 4; ++r) l_i[r] = 0.f;
      qt = qtB; n_seg = nB; segbase = nA;
    }
    int tloc = tt - segbase;
    int kv0 = tloc * 64;

    // S = Q K^T
    f32x4 s[4];
    __builtin_amdgcn_s_setprio(1);
    #pragma unroll
    for (int c = 0; c < 4; ++c) {
      f32x4 acc = zero4;
      #pragma unroll
      for (int kt = 0; kt < 4; ++kt) {
        int po = ((kt*4 + quad) ^ (l16 & 7)) * 8;
        bf16x8 kf = *(const bf16x8*)&Ks[buf][(c*16 + l16)*128 + po];
        acc = __builtin_amdgcn_mfma_f32_16x16x32_bf16(qf[kt], kf, acc, 0, 0, 0);
      }
      s[c] = acc;
    }
    __builtin_amdgcn_s_setprio(0);

    bool domask = (tloc == n_seg - 1);
    int qgb = qt*64 + w*16 + quad*4;
    #pragma unroll
    for (int c = 0; c < 4; ++c) {
      int kg = kv0 + c*16 + l16;
      #pragma unroll
      for (int r = 0; r < 4; ++r) {
        float t = s[c][r] * FL_C1 - FL_C2;
        if (domask && kg > qgb + r) t = -1000.0f;
        float pv = exp2f(t);
        Ps[w][(quad*4 + r)*72 + c*16 + l16] = f2bf(pv);
      }
    }
    asm volatile("s_waitcnt lgkmcnt(0)" ::: "memory");
    bf16x8 pa0 = *(const bf16x8*)&Ps[w][l16*72 + quad*8];
    bf16x8 pa1 = *(const bf16x8*)&Ps[w][l16*72 + 32 + quad*8];

    __builtin_amdgcn_s_setprio(1);
    f32x4 racc = __builtin_amdgcn_mfma_f32_16x16x32_bf16(pa0, ones, zero4, 0, 0, 0);
    racc = __builtin_amdgcn_mfma_f32_16x16x32_bf16(pa1, ones, racc, 0, 0, 0);
    #pragma unroll
    for (int r = 0; r < 4; ++r) l_i[r] += racc[r];

    #pragma unroll
    for (int c8 = 0; c8 < 8; ++c8) {
      int po0 = ((0*4 + quad) ^ (l16 & 7)) * 8;
      int po1 = ((1*4 + quad) ^ (l16 & 7)) * 8;
      bf16x8 v0 = *(const bf16x8*)&Vts[buf][(c8*16 + l16)*64 + po0];
      bf16x8 v1 = *(const bf16x8*)&Vts[buf][(c8*16 + l16)*64 + po1];
      o[c8] = __builtin_amdgcn_mfma_f32_16x16x32_bf16(pa0, v0, o[c8], 0, 0, 0);
      o[c8] = __builtin_amdgcn_mfma_f32_16x16x32_bf16(pa1, v1, o[c8], 0, 0, 0);
    }
    __builtin_amdgcn_s_setprio(0);
  }
  flushO(qtB);
}

// ---------------------------------------------------------------------------
extern "C" void kernel_launch(void* const* d_in, const int* in_sizes, int n_in,
                              void* d_out, int out_size, void* d_ws, size_t ws_size,
                              hipStream_t stream) {
  const void* x    = d_in[0];
  const void* ve   = d_in[1];
  const void* cosb = d_in[2];
  const void* sinb = d_in[3];
  const void* Wq   = d_in[4];
  const void* Wk   = d_in[5];
  const void* Wv   = d_in[6];
  const void* Wg   = d_in[7];
  const void* Wp   = d_in[8];
  float* out = (float*)d_out;

  int*   flag = (int*)d_ws;
  short* base = (short*)d_ws + 256;
  short* wt0 = base;                       // 4M: Wq^T, then Wp^T
  short* wtk = base + 4194304L;            // 4M: Wk^T (dead after QKV gemm)
  short* wtv = base + 8388608L;            // 4M: Wv^T (dead after QKV gemm)
  short* Vt  = base + 4194304L;            // 8M: aliases wtk+wtv
  short* xb  = base + 12582912L;           // 8M: bf16 x (dead after pointwise)
  short* Y   = base + 12582912L;           // 8M: aliases xb
  short* Qr  = base + 20971520L;           // 8M
  short* Kr  = base + 29360128L;           // 8M
  short* Vr  = base + 37748736L;           // 8M

  detect_dtype<<<1, 64, 0, stream>>>((const short*)x, flag);
  convert_x<<<4096, 256, 0, stream>>>(x, xb, flag);
  transpose_w<<<dim3(64, 64, 3), dim3(32, 8), 0, stream>>>(Wq, wt0, Wk, wtk, Wv, wtv, flag);
  gemm_bt<short><<<dim3(16, 32, 3), 256, 0, stream>>>(xb, wt0, wtk, wtv, Qr, Kr, Vr, 4096, 2048, 2048);
  transpose_w<<<dim3(64, 64, 1), dim3(32, 8), 0, stream>>>(Wp, wt0, Wp, wt0, Wp, wt0, flag);
  pointwise<<<dim3(4096), 256, 0, stream>>>(xb, ve, cosb, sinb, Wg, flag, Qr, Kr, Vr);
  transpose_v<<<dim3(64, 4, 32), dim3(32, 8), 0, stream>>>(Vr, Vt);
  flash<<<dim3(16, 32), 256, 0, stream>>>(Qr, Kr, Vt, Y);
  gemm_bt<float><<<dim3(16, 32, 1), 256, 0, stream>>>(Y, wt0, wt0, wt0, out, out, out, 4096, 2048, 2048);
}

// Round 6
// 448.396 us; speedup vs baseline: 1.1059x; 1.0186x over previous
//
#include <hip/hip_runtime.h>
#include <stdint.h>

typedef short bf16x8 __attribute__((ext_vector_type(8)));
typedef float f32x4 __attribute__((ext_vector_type(4)));

#define ASYNC16(g, l) __builtin_amdgcn_global_load_lds( \
    (const __attribute__((address_space(1))) unsigned int*)(g), \
    (__attribute__((address_space(3))) unsigned int*)(l), 16, 0, 0)

__device__ __forceinline__ float bf2f(short u) {
  union { unsigned int i; float f; } v;
  v.i = ((unsigned int)(unsigned short)u) << 16;
  return v.f;
}
__device__ __forceinline__ short f2bf(float f) {
  union { float f; unsigned int i; } v;
  v.f = f;
  return (short)(unsigned short)((v.i + 0x8000u) >> 16);
}
__device__ __forceinline__ float ldf(const void* p, long i, int isbf) {
  return isbf ? bf2f(((const short*)p)[i]) : ((const float*)p)[i];
}

// ---------------------------------------------------------------------------
__global__ void detect_dtype(const short* __restrict__ x, int* __restrict__ flag) {
  if (threadIdx.x == 0 && blockIdx.x == 0) {
    int cnt = 0;
    for (int i = 0; i < 128; ++i) {
      int e = (((unsigned short)x[i]) >> 7) & 0xFF;
      if (e >= 110 && e <= 136) ++cnt;
    }
    *flag = (cnt >= 120) ? 1 : 0;
  }
}

__global__ __launch_bounds__(256) void convert_x(
    const void* __restrict__ xin, short* __restrict__ xb, const int* __restrict__ flag) {
  long i = (long)blockIdx.x * 2048 + (long)threadIdx.x * 8;
  if (*flag) {
    *(bf16x8*)(xb + i) = *(const bf16x8*)((const short*)xin + i);
  } else {
    const float* xf = (const float*)xin;
    short tmp[8];
    #pragma unroll
    for (int j = 0; j < 8; ++j) tmp[j] = f2bf(xf[i + j]);
    *(bf16x8*)(xb + i) = *(bf16x8*)tmp;
  }
}

// ---------------------------------------------------------------------------
__global__ __launch_bounds__(256) void transpose_w(
    const void* __restrict__ S0, short* __restrict__ D0,
    const void* __restrict__ S1, short* __restrict__ D1,
    const void* __restrict__ S2, short* __restrict__ D2,
    const int* __restrict__ flag)
{
  int z = blockIdx.z;
  const void* S = (z == 0) ? S0 : (z == 1) ? S1 : S2;
  short* D = (z == 0) ? D0 : (z == 1) ? D1 : D2;
  int isbf = *flag;
  __shared__ short tile[32][33];
  int c0 = blockIdx.x * 32, r0 = blockIdx.y * 32;
  int tx = threadIdx.x, ty = threadIdx.y;
  #pragma unroll
  for (int i = 0; i < 4; ++i)
    tile[ty + 8*i][tx] = f2bf(ldf(S, (long)(r0 + ty + 8*i) * 2048 + c0 + tx, isbf));
  __syncthreads();
  #pragma unroll
  for (int i = 0; i < 4; ++i)
    D[(long)(c0 + ty + 8*i) * 2048 + r0 + tx] = tile[tx][ty + 8*i];
}

__global__ __launch_bounds__(256) void transpose_v(
    const short* __restrict__ Vr, short* __restrict__ Vt)
{
  __shared__ short tile[32][33];
  int bh = blockIdx.z;
  int b = bh >> 4, h = bh & 15;
  int t0 = blockIdx.x * 32, d0 = blockIdx.y * 32;
  int tx = threadIdx.x, ty = threadIdx.y;
  #pragma unroll
  for (int i = 0; i < 4; ++i)
    tile[ty + 8*i][tx] = Vr[(long)(b*2048 + t0 + ty + 8*i) * 2048 + h*128 + d0 + tx];
  __syncthreads();
  #pragma unroll
  for (int i = 0; i < 4; ++i)
    Vt[((long)bh * 128 + d0 + ty + 8*i) * 2048 + t0 + tx] = tile[tx][ty + 8*i];
}

// ---------------------------------------------------------------------------
// gemm_bt: proven R0 128x128-tile kernel + T1 XCD swizzle (FETCH -40%
// verified in R4; time-neutral — structure-bound at ~845 TF).
// ---------------------------------------------------------------------------
template<typename OutT>
__global__ __launch_bounds__(256) void gemm_bt(
    const short* __restrict__ A,
    const short* __restrict__ B0, const short* __restrict__ B1, const short* __restrict__ B2,
    OutT* __restrict__ C0, OutT* __restrict__ C1, OutT* __restrict__ C2,
    int M, int N, int K)
{
  int z = blockIdx.z;
  const short* Bt = (z == 0) ? B0 : (z == 1) ? B1 : B2;
  OutT* C = (z == 0) ? C0 : (z == 1) ? C1 : C2;

  // XCD swizzle: d%8 = XCD; chunk = 8x8 blocks (1024 rows x 1024 cols)
  int d = blockIdx.y * 16 + blockIdx.x;
  int xcd = d & 7, ci = d >> 3;
  int bx = (xcd & 1) * 8 + (ci & 7);
  int by = (xcd >> 1) * 8 + (ci >> 3);
  int m0 = by * 128, n0 = bx * 128;

  int tid = threadIdx.x;
  int lane = tid & 63, w = tid >> 6;
  int quad = lane >> 4, l16 = lane & 15;
  int wm = w >> 1, wn = w & 1;

  __shared__ short As[128][64];
  __shared__ short Bs[128][64];

  f32x4 zero4 = {0.f, 0.f, 0.f, 0.f};
  f32x4 acc[4][4];
  #pragma unroll
  for (int i = 0; i < 4; ++i)
    #pragma unroll
    for (int j = 0; j < 4; ++j) acc[i][j] = zero4;

  int r8 = lane >> 3;
  int srow = w * 32 + r8;
  int scol = ((lane & 7) ^ r8) * 8;

  for (int k0 = 0; k0 < K; k0 += 64) {
    #pragma unroll
    for (int i = 0; i < 4; ++i) {
      ASYNC16(A  + (long)(m0 + srow + i*8) * K + k0 + scol, &As[w*32 + i*8][0]);
      ASYNC16(Bt + (long)(n0 + srow + i*8) * K + k0 + scol, &Bs[w*32 + i*8][0]);
    }
    __syncthreads();
    #pragma unroll
    for (int kt = 0; kt < 2; ++kt) {
      int po = ((kt*4 + quad) ^ (l16 & 7)) * 8;
      bf16x8 af[4], bfr[4];
      #pragma unroll
      for (int i = 0; i < 4; ++i)
        af[i] = *(const bf16x8*)&As[wm*64 + i*16 + l16][po];
      #pragma unroll
      for (int j = 0; j < 4; ++j)
        bfr[j] = *(const bf16x8*)&Bs[wn*64 + j*16 + l16][po];
      #pragma unroll
      for (int i = 0; i < 4; ++i)
        #pragma unroll
        for (int j = 0; j < 4; ++j)
          acc[i][j] = __builtin_amdgcn_mfma_f32_16x16x32_bf16(af[i], bfr[j], acc[i][j], 0, 0, 0);
    }
    __syncthreads();
  }

  #pragma unroll
  for (int i = 0; i < 4; ++i)
    #pragma unroll
    for (int j = 0; j < 4; ++j) {
      int row = m0 + wm*64 + i*16 + quad*4;
      int col = n0 + wn*64 + j*16 + l16;
      #pragma unroll
      for (int r = 0; r < 4; ++r) {
        float v = acc[i][j][r];
        if constexpr (sizeof(OutT) == 4)
          C[(long)(row + r) * N + col] = v;
        else
          C[(long)(row + r) * N + col] = (OutT)f2bf(v);
      }
    }
}

// ---------------------------------------------------------------------------
__global__ __launch_bounds__(256) void pointwise(
    const short* __restrict__ xb, const void* __restrict__ ve,
    const void* __restrict__ cosb, const void* __restrict__ sinb,
    const void* __restrict__ Wg, const int* __restrict__ flag,
    short* __restrict__ Qr, short* __restrict__ Kr, short* __restrict__ Vr)
{
  int row = blockIdx.x;
  int tid = threadIdx.x;
  int isbf = *flag;
  __shared__ float xg[32];
  __shared__ float gates[16];
  if (tid < 32) xg[tid] = bf2f(xb[(long)row * 2048 + tid]);
  __syncthreads();
  if (tid < 16) {
    float g = 0.f;
    #pragma unroll
    for (int i = 0; i < 32; ++i) g += xg[i] * ldf(Wg, i*16 + tid, isbf);
    gates[tid] = 2.0f / (1.0f + __expf(-g));
  }
  __syncthreads();
  {
    // vectorized gate update: each thread handles 8 contiguous channels
    int idx = tid * 8;
    int h = idx >> 7;
    long p = (long)row * 2048 + idx;
    float g = gates[h];
    bf16x8 vv = *(bf16x8*)(Vr + p);
    short tmp[8];
    if (isbf) {
      bf16x8 vb = *(const bf16x8*)((const short*)ve + p);
      #pragma unroll
      for (int j = 0; j < 8; ++j) tmp[j] = f2bf(bf2f(vv[j]) + g * bf2f(vb[j]));
    } else {
      const float* vf = (const float*)ve;
      f32x4 a = *(const f32x4*)(vf + p);
      f32x4 b2 = *(const f32x4*)(vf + p + 4);
      #pragma unroll
      for (int j = 0; j < 4; ++j) tmp[j]     = f2bf(bf2f(vv[j])     + g * a[j]);
      #pragma unroll
      for (int j = 0; j < 4; ++j) tmp[j + 4] = f2bf(bf2f(vv[j + 4]) + g * b2[j]);
    }
    *(bf16x8*)(Vr + p) = *(bf16x8*)tmp;
  }
  int lane = tid & 63, w = tid >> 6;
  int t = row & 2047;
  #pragma unroll
  for (int it = 0; it < 8; ++it) {
    int unit = it * 4 + w;
    short* P = (unit < 16) ? Qr : Kr;
    int h = unit & 15;
    long base = (long)row * 2048 + h * 128;
    float x1 = bf2f(P[base + lane]);
    float x2 = bf2f(P[base + lane + 64]);
    float c = ldf(cosb, t*64 + lane, isbf);
    float s = ldf(sinb, t*64 + lane, isbf);
    float r1 = x1 * c + x2 * s;
    float r2 = -x1 * s + x2 * c;
    float ss = r1*r1 + r2*r2;
    #pragma unroll
    for (int off = 32; off; off >>= 1) ss += __shfl_xor(ss, off);
    float rn = rsqrtf(ss * (1.0f/128.0f) + 1e-6f);
    P[base + lane]      = f2bf(r1 * rn);
    P[base + lane + 64] = f2bf(r2 * rn);
  }
}

// ---------------------------------------------------------------------------
// Flash v4: JOINT q-pair processing.  Each block owns q-tiles (bx, 31-bx)
// and iterates k-tiles 0..nB-1 ONCE, computing segment B every iteration
// and segment A while k <= qtA.  vs v3 (sequential segments, nA+nB=34
// iterations): iterations drop to nB (17..32, avg 24.5, -28%), K/V staging
// traffic -28%, and every block strictly faster than before (32 < 34).
// Double O/l/Q register state; __launch_bounds__(256,2) caps VGPR at 256
// to hold 2 blocks/CU (LDS 73 KB).  Ps reuse across segments is safe:
// same-wave DS ops execute in order (B's pa reads precede A's Ps writes
// in program order).
// ---------------------------------------------------------------------------
#define FL_C1 0.12751741f
#define FL_C2 16.321698f

__global__ __launch_bounds__(256, 2) void flash(
    const short* __restrict__ Q, const short* __restrict__ K,
    const short* __restrict__ Vt, short* __restrict__ Y)
{
  int d = blockIdx.y * 16 + blockIdx.x;
  int xcd = d & 7, ci = d >> 3;
  int bx = ci & 15;
  int bh = xcd * 4 + (ci >> 4);
  int b = bh >> 4, h = bh & 15;
  int tid = threadIdx.x;
  int lane = tid & 63, w = tid >> 6;
  int quad = lane >> 4, l16 = lane & 15;

  __shared__ short Ks[2][64*128];
  __shared__ short Vts[2][128*64];
  __shared__ short Ps[4][16*72];

  int qtA = bx, qtB = 31 - bx;
  int nA = qtA + 1, nB = qtB + 1;      // nB >= nA + 1 always

  int kkey = tid >> 4;
  int klo  = (tid & 15) ^ (kkey & 7);
  int vd   = tid >> 3;
  int vlo  = (tid & 7) ^ (vd & 7);
  const short* Kbase = K + (long)(b*2048 + kkey) * 2048 + h*128 + klo*8;
  const short* Vbase = Vt + ((long)bh*128 + vd) * 2048 + vlo*8;

  f32x4 zero4 = {0.f, 0.f, 0.f, 0.f};
  f32x4 oA[8], oB[8];
  float lA[4], lB[4];
  bf16x8 qfA[4], qfB[4];
  bf16x8 ones;
  #pragma unroll
  for (int j = 0; j < 8; ++j) ones[j] = (short)0x3F80;

  int pv0 = ((0*4 + quad) ^ (l16 & 7)) * 8;
  int pv1 = ((1*4 + quad) ^ (l16 & 7)) * 8;

  auto stage = [&](int tl, int bufp) {
    long ko = (long)tl * 64 * 2048;
    int  vo = tl * 64;
    #pragma unroll
    for (int i = 0; i < 4; ++i)
      ASYNC16(Kbase + ko + (long)i*16*2048, &Ks[bufp][(i*16 + w*4)*128]);
    #pragma unroll
    for (int i = 0; i < 4; ++i)
      ASYNC16(Vbase + vo + (long)i*32*2048, &Vts[bufp][(i*32 + w*8)*64]);
  };
  auto loadQ = [&](int qt, bf16x8 (&qf)[4]) {
    const short* Qb = Q + (long)(b*2048 + qt*64 + w*16 + l16) * 2048 + h*128;
    #pragma unroll
    for (int kt = 0; kt < 4; ++kt)
      qf[kt] = *(const bf16x8*)(Qb + kt*32 + quad*8);
  };
  auto flushO = [&](int qt, f32x4 (&o)[8], float (&l)[4]) {
    #pragma unroll
    for (int r = 0; r < 4; ++r) {
      float inv = 1.0f / fmaxf(l[r], 1e-30f);
      short* yp = Y + (long)(b*2048 + qt*64 + w*16 + quad*4 + r) * 2048 + h*128;
      #pragma unroll
      for (int c8 = 0; c8 < 8; ++c8)
        yp[c8*16 + l16] = f2bf(o[c8][r] * inv);
    }
  };
  auto doTile = [&](bf16x8 (&qf)[4], f32x4 (&o)[8], float (&l)[4],
                    int qt, bool domask, int buf, int kv0) {
    // S = Q K^T  (16 q-rows x 64 keys per wave)
    f32x4 s[4];
    __builtin_amdgcn_s_setprio(1);
    #pragma unroll
    for (int c = 0; c < 4; ++c) {
      f32x4 acc = zero4;
      #pragma unroll
      for (int kt = 0; kt < 4; ++kt) {
        int po = ((kt*4 + quad) ^ (l16 & 7)) * 8;
        bf16x8 kf = *(const bf16x8*)&Ks[buf][(c*16 + l16)*128 + po];
        acc = __builtin_amdgcn_mfma_f32_16x16x32_bf16(qf[kt], kf, acc, 0, 0, 0);
      }
      s[c] = acc;
    }
    __builtin_amdgcn_s_setprio(0);

    // fixed-max softmax: p = 2^(s*C1 - C2); mask only on diagonal step
    int qgb = qt*64 + w*16 + quad*4;
    #pragma unroll
    for (int c = 0; c < 4; ++c) {
      int kg = kv0 + c*16 + l16;
      #pragma unroll
      for (int r = 0; r < 4; ++r) {
        float t = s[c][r] * FL_C1 - FL_C2;
        if (domask && kg > qgb + r) t = -1000.0f;
        Ps[w][(quad*4 + r)*72 + c*16 + l16] = f2bf(exp2f(t));
      }
    }
    asm volatile("s_waitcnt lgkmcnt(0)" ::: "memory");
    bf16x8 pa0 = *(const bf16x8*)&Ps[w][l16*72 + quad*8];
    bf16x8 pa1 = *(const bf16x8*)&Ps[w][l16*72 + 32 + quad*8];

    __builtin_amdgcn_s_setprio(1);
    f32x4 racc = __builtin_amdgcn_mfma_f32_16x16x32_bf16(pa0, ones, zero4, 0, 0, 0);
    racc = __builtin_amdgcn_mfma_f32_16x16x32_bf16(pa1, ones, racc, 0, 0, 0);
    #pragma unroll
    for (int r = 0; r < 4; ++r) l[r] += racc[r];

    #pragma unroll
    for (int c8 = 0; c8 < 8; ++c8) {
      bf16x8 v0 = *(const bf16x8*)&Vts[buf][(c8*16 + l16)*64 + pv0];
      bf16x8 v1 = *(const bf16x8*)&Vts[buf][(c8*16 + l16)*64 + pv1];
      o[c8] = __builtin_amdgcn_mfma_f32_16x16x32_bf16(pa0, v0, o[c8], 0, 0, 0);
      o[c8] = __builtin_amdgcn_mfma_f32_16x16x32_bf16(pa1, v1, o[c8], 0, 0, 0);
    }
    __builtin_amdgcn_s_setprio(0);
  };

  #pragma unroll
  for (int c = 0; c < 8; ++c) { oA[c] = zero4; oB[c] = zero4; }
  #pragma unroll
  for (int r = 0; r < 4; ++r) { lA[r] = 0.f; lB[r] = 0.f; }
  loadQ(qtA, qfA);
  loadQ(qtB, qfB);
  stage(0, 0);

  for (int tt = 0; tt < nB; ++tt) {
    int buf = tt & 1;
    asm volatile("s_waitcnt vmcnt(0)" ::: "memory");
    __builtin_amdgcn_s_barrier();
    if (tt + 1 < nB) stage(tt + 1, buf ^ 1);
    int kv0 = tt * 64;

    doTile(qfB, oB, lB, qtB, tt == nB - 1, buf, kv0);
    if (tt < nA)
      doTile(qfA, oA, lA, qtA, tt == nA - 1, buf, kv0);
  }
  flushO(qtB, oB, lB);
  flushO(qtA, oA, lA);
}

// ---------------------------------------------------------------------------
extern "C" void kernel_launch(void* const* d_in, const int* in_sizes, int n_in,
                              void* d_out, int out_size, void* d_ws, size_t ws_size,
                              hipStream_t stream) {
  const void* x    = d_in[0];
  const void* ve   = d_in[1];
  const void* cosb = d_in[2];
  const void* sinb = d_in[3];
  const void* Wq   = d_in[4];
  const void* Wk   = d_in[5];
  const void* Wv   = d_in[6];
  const void* Wg   = d_in[7];
  const void* Wp   = d_in[8];
  float* out = (float*)d_out;

  int*   flag = (int*)d_ws;
  short* base = (short*)d_ws + 256;
  short* wt0 = base;                       // 4M: Wq^T, then Wp^T
  short* wtk = base + 4194304L;            // 4M: Wk^T (dead after QKV gemm)
  short* wtv = base + 8388608L;            // 4M: Wv^T (dead after QKV gemm)
  short* Vt  = base + 4194304L;            // 8M: aliases wtk+wtv
  short* xb  = base + 12582912L;           // 8M: bf16 x (dead after pointwise)
  short* Y   = base + 12582912L;           // 8M: aliases xb
  short* Qr  = base + 20971520L;           // 8M
  short* Kr  = base + 29360128L;           // 8M
  short* Vr  = base + 37748736L;           // 8M

  detect_dtype<<<1, 64, 0, stream>>>((const short*)x, flag);
  convert_x<<<4096, 256, 0, stream>>>(x, xb, flag);
  transpose_w<<<dim3(64, 64, 3), dim3(32, 8), 0, stream>>>(Wq, wt0, Wk, wtk, Wv, wtv, flag);
  gemm_bt<short><<<dim3(16, 32, 3), 256, 0, stream>>>(xb, wt0, wtk, wtv, Qr, Kr, Vr, 4096, 2048, 2048);
  transpose_w<<<dim3(64, 64, 1), dim3(32, 8), 0, stream>>>(Wp, wt0, Wp, wt0, Wp, wt0, flag);
  pointwise<<<dim3(4096), 256, 0, stream>>>(xb, ve, cosb, sinb, Wg, flag, Qr, Kr, Vr);
  transpose_v<<<dim3(64, 4, 32), dim3(32, 8), 0, stream>>>(Vr, Vt);
  flash<<<dim3(16, 32), 256, 0, stream>>>(Qr, Kr, Vt, Y);
  gemm_bt<float><<<dim3(16, 32, 1), 256, 0, stream>>>(Y, wt0, wt0, wt0, out, out, out, 4096, 2048, 2048);
}